// Round 2
// baseline (1230.704 us; speedup 1.0000x reference)
//
#include <hip/hip_runtime.h>
#include <hip/hip_bf16.h>

// Problem constants
#define NB 64    // batch
#define TT 512   // timesteps
#define HH 512   // hidden
#define DD 512   // input dim

typedef __attribute__((ext_vector_type(8))) __bf16 bf16x8;
typedef __attribute__((ext_vector_type(4))) float f32x4;

__device__ __forceinline__ unsigned short f2bf_rn(float f) {
    union { float f; unsigned u; } v; v.f = f;
    unsigned r = v.u + 0x7FFFu + ((v.u >> 16) & 1u);
    return (unsigned short)(r >> 16);
}
__device__ __forceinline__ float bf2f(unsigned short s) {
    union { unsigned u; float f; } v; v.u = ((unsigned)s) << 16;
    return v.f;
}

// ---------------------------------------------------------------------------
// Kernel 1: Wt[n][k]   = bf16_hi(Wx[k][n])   (n in [0,512), k in [0,512))
//           Wt[n][512+k] = bf16_lo(Wx[k][n])
// ---------------------------------------------------------------------------
__global__ __launch_bounds__(256) void wt_kernel(const float* __restrict__ Wx,
                                                 unsigned short* __restrict__ Wt) {
    const int bk = blockIdx.x >> 3, bn = blockIdx.x & 7;
    const int k0 = bk * 64, n0 = bn * 64;
    __shared__ float tile[64][65];
    const int t = threadIdx.x;
    const int kr = t >> 2, seg = t & 3;
    const float4* src = (const float4*)&Wx[(k0 + kr) * HH + n0 + seg * 16];
    float4 a = src[0], b = src[1], c = src[2], d = src[3];
    float vv[16];
    *(float4*)&vv[0] = a; *(float4*)&vv[4] = b; *(float4*)&vv[8] = c; *(float4*)&vv[12] = d;
#pragma unroll
    for (int q = 0; q < 16; ++q) tile[kr][seg * 16 + q] = vv[q];
    __syncthreads();
    const int nr = t >> 2;
    unsigned hu[8], lu[8];
#pragma unroll
    for (int i = 0; i < 8; ++i) {
        float f0 = tile[seg * 16 + 2 * i + 0][nr];
        float f1 = tile[seg * 16 + 2 * i + 1][nr];
        unsigned short h0 = f2bf_rn(f0); unsigned short l0 = f2bf_rn(f0 - bf2f(h0));
        unsigned short h1 = f2bf_rn(f1); unsigned short l1 = f2bf_rn(f1 - bf2f(h1));
        hu[i] = (unsigned)h0 | ((unsigned)h1 << 16);
        lu[i] = (unsigned)l0 | ((unsigned)l1 << 16);
    }
    unsigned short* dh = &Wt[(n0 + nr) * 1024 + k0 + seg * 16];
    unsigned short* dl = dh + 512;
    ((uint4*)dh)[0] = make_uint4(hu[0], hu[1], hu[2], hu[3]);
    ((uint4*)dh)[1] = make_uint4(hu[4], hu[5], hu[6], hu[7]);
    ((uint4*)dl)[0] = make_uint4(lu[0], lu[1], lu[2], lu[3]);
    ((uint4*)dl)[1] = make_uint4(lu[4], lu[5], lu[6], lu[7]);
}

// ---------------------------------------------------------------------------
// Kernel 2: projection GEMM  out[i][j] = sum_k x[i][k]*Wx[k][j] + b[j]
// split-bf16 (hi*hi + hi*lo + lo*hi) via MFMA, fp32-accurate.
// ---------------------------------------------------------------------------
#define LDA 72
__global__ __launch_bounds__(256) void proj_kernel(const float* __restrict__ x,
                                                   const unsigned short* __restrict__ Wt,
                                                   const float* __restrict__ bias,
                                                   float* __restrict__ out) {
    __shared__ __align__(16) unsigned short a_hi[64 * LDA];
    __shared__ __align__(16) unsigned short a_lo[64 * LDA];
    __shared__ __align__(16) unsigned short b_hi[64 * LDA];
    __shared__ __align__(16) unsigned short b_lo[64 * LDA];

    const int bx = blockIdx.x;
    const int i0 = (bx >> 3) * 64;
    const int n0 = (bx & 7) * 64;
    const int t = threadIdx.x;
    const int row = t >> 2, seg = t & 3;
    const int lane = t & 63, wid = t >> 6;
    const int wm = (wid >> 1) * 32, wn = (wid & 1) * 32;
    const int fr = lane & 15;

    f32x4 acc00 = {0.f, 0.f, 0.f, 0.f}, acc01 = acc00, acc10 = acc00, acc11 = acc00;

    for (int kc = 0; kc < 8; ++kc) {
        __syncthreads();
        {
            const float4* src = (const float4*)&x[(i0 + row) * DD + kc * 64 + seg * 16];
            float4 a = src[0], b = src[1], c = src[2], d = src[3];
            float vv[16];
            *(float4*)&vv[0] = a; *(float4*)&vv[4] = b; *(float4*)&vv[8] = c; *(float4*)&vv[12] = d;
            unsigned hu[8], lu[8];
#pragma unroll
            for (int i = 0; i < 8; ++i) {
                unsigned short h0 = f2bf_rn(vv[2 * i]); unsigned short l0 = f2bf_rn(vv[2 * i] - bf2f(h0));
                unsigned short h1 = f2bf_rn(vv[2 * i + 1]); unsigned short l1 = f2bf_rn(vv[2 * i + 1] - bf2f(h1));
                hu[i] = (unsigned)h0 | ((unsigned)h1 << 16);
                lu[i] = (unsigned)l0 | ((unsigned)l1 << 16);
            }
            uint4* dh = (uint4*)&a_hi[row * LDA + seg * 16];
            uint4* dl = (uint4*)&a_lo[row * LDA + seg * 16];
            dh[0] = make_uint4(hu[0], hu[1], hu[2], hu[3]);
            dh[1] = make_uint4(hu[4], hu[5], hu[6], hu[7]);
            dl[0] = make_uint4(lu[0], lu[1], lu[2], lu[3]);
            dl[1] = make_uint4(lu[4], lu[5], lu[6], lu[7]);
        }
        {
            const uint4* sh = (const uint4*)&Wt[(n0 + row) * 1024 + kc * 64 + seg * 16];
            const uint4* sl = (const uint4*)&Wt[(n0 + row) * 1024 + 512 + kc * 64 + seg * 16];
            uint4 h0v = sh[0], h1v = sh[1], l0v = sl[0], l1v = sl[1];
            uint4* dh = (uint4*)&b_hi[row * LDA + seg * 16];
            uint4* dl = (uint4*)&b_lo[row * LDA + seg * 16];
            dh[0] = h0v; dh[1] = h1v; dl[0] = l0v; dl[1] = l1v;
        }
        __syncthreads();
#pragma unroll
        for (int s = 0; s < 2; ++s) {
            const int ko = s * 32 + (lane >> 4) * 8;
            bf16x8 ah0 = *(const bf16x8*)&a_hi[(wm + fr) * LDA + ko];
            bf16x8 ah1 = *(const bf16x8*)&a_hi[(wm + 16 + fr) * LDA + ko];
            bf16x8 al0 = *(const bf16x8*)&a_lo[(wm + fr) * LDA + ko];
            bf16x8 al1 = *(const bf16x8*)&a_lo[(wm + 16 + fr) * LDA + ko];
            bf16x8 bh0 = *(const bf16x8*)&b_hi[(wn + fr) * LDA + ko];
            bf16x8 bh1 = *(const bf16x8*)&b_hi[(wn + 16 + fr) * LDA + ko];
            bf16x8 bl0 = *(const bf16x8*)&b_lo[(wn + fr) * LDA + ko];
            bf16x8 bl1 = *(const bf16x8*)&b_lo[(wn + 16 + fr) * LDA + ko];
            acc00 = __builtin_amdgcn_mfma_f32_16x16x32_bf16(ah0, bh0, acc00, 0, 0, 0);
            acc00 = __builtin_amdgcn_mfma_f32_16x16x32_bf16(ah0, bl0, acc00, 0, 0, 0);
            acc00 = __builtin_amdgcn_mfma_f32_16x16x32_bf16(al0, bh0, acc00, 0, 0, 0);
            acc01 = __builtin_amdgcn_mfma_f32_16x16x32_bf16(ah0, bh1, acc01, 0, 0, 0);
            acc01 = __builtin_amdgcn_mfma_f32_16x16x32_bf16(ah0, bl1, acc01, 0, 0, 0);
            acc01 = __builtin_amdgcn_mfma_f32_16x16x32_bf16(al0, bh1, acc01, 0, 0, 0);
            acc10 = __builtin_amdgcn_mfma_f32_16x16x32_bf16(ah1, bh0, acc10, 0, 0, 0);
            acc10 = __builtin_amdgcn_mfma_f32_16x16x32_bf16(ah1, bl0, acc10, 0, 0, 0);
            acc10 = __builtin_amdgcn_mfma_f32_16x16x32_bf16(al1, bh0, acc10, 0, 0, 0);
            acc11 = __builtin_amdgcn_mfma_f32_16x16x32_bf16(ah1, bh1, acc11, 0, 0, 0);
            acc11 = __builtin_amdgcn_mfma_f32_16x16x32_bf16(ah1, bl1, acc11, 0, 0, 0);
            acc11 = __builtin_amdgcn_mfma_f32_16x16x32_bf16(al1, bh1, acc11, 0, 0, 0);
        }
    }
    const float bc0 = bias[n0 + wn + fr];
    const float bc1 = bias[n0 + wn + 16 + fr];
#pragma unroll
    for (int r = 0; r < 4; ++r) {
        int rw0 = i0 + wm + (lane >> 4) * 4 + r;
        int rw1 = rw0 + 16;
        out[rw0 * HH + n0 + wn + fr]      = acc00[r] + bc0;
        out[rw0 * HH + n0 + wn + 16 + fr] = acc01[r] + bc1;
        out[rw1 * HH + n0 + wn + fr]      = acc10[r] + bc0;
        out[rw1 * HH + n0 + wn + 16 + fr] = acc11[r] + bc1;
    }
}

// ---------------------------------------------------------------------------
// Kernel 3: recurrence, TWO phase-shifted batches per block.
// grid 128 blocks x 512 threads (1 block/CU on 256 CUs).
// block b: pair p = b>>2 (batches gA=2p, gB=2p+1), slice s = b&3
// (columns [s*128, s*128+128)). Thread: jl=tid&127 (local col), kg=tid>>7
// (k-quarter), w[128] of Wh in regs (SHARED between both batches).
//
// Per round t (advances both batches one step):
//   [issue poll B(t-1)] FMA_A(hsA) -> red; bar;
//   kg0: aggregate+tanh -> store A(t) tag t+1 (LLC) + hsA local + xwA prefetch
//   remote threads: check/spin B poll, stage hsB; bar;
//   [issue poll A(t)]   FMA_B(hsB) -> red; bar;
//   kg0: aggregate B, store B(t); remote: check/spin A poll, stage hsA; bar.
// The poll for one batch is issued BEFORE the other batch's FMA, so the LLC
// round-trip of each exchange hides under ~1000cy of the other batch's
// compute: expected spin count ~0, detect latency off the critical path.
// Slot-reuse safety: producer reaches tag t+2 only after polling tag t+1
// from all peers, which requires all peers consumed tag t. Exact-tag match
// on 8B single-copy-atomic words; no fences needed.
// ---------------------------------------------------------------------------
__global__ __launch_bounds__(512, 2) void rec_kernel(const float* __restrict__ h0,
                                                     const float* __restrict__ Wh,
                                                     float* __restrict__ out,
                                                     unsigned long long* __restrict__ hbuf2) {
    const int b = blockIdx.x;
    const int p = b >> 2;            // pair index 0..31
    const int s = b & 3;             // col slice
    const int gA = 2 * p, gB = 2 * p + 1;
    const int c0 = s * 128;
    const int tid = threadIdx.x;
    const int jl = tid & 127;
    const int kg = tid >> 7;
    const int kb = kg * 128;
    const int j = c0 + jl;
    // rem is uniform per wave (waves are 64-aligned, slices 128-aligned)
    const bool rem = (tid < c0) || (tid >= c0 + 128);

    // Wh quarter into registers (shared by both batches)
    float w[128];
#pragma unroll
    for (int r = 0; r < 128; ++r) w[r] = Wh[(kb + r) * HH + j];

    __shared__ float hsA[HH], hsB[HH];
    __shared__ float red[3][128];

    float xwA = 0.f, xwB = 0.f;
    if (kg == 0) {
        xwA = out[(gA * TT + 0) * HH + j];
        xwB = out[(gB * TT + 0) * HH + j];
    }
    hsA[tid] = h0[gA * HH + tid];
    hsB[tid] = h0[gB * HH + tid];
    __syncthreads();

#pragma unroll 1
    for (int t = 0; t < TT; ++t) {
        // ================= phase A: produce A(t), stage B(t-1) =============
        // early-issue poll for B(t-1): stored with tag t at slot (t+1)&1
        const unsigned long long* slotB =
            &hbuf2[(((unsigned)(t + 1)) & 1u) * (NB * HH) + gB * HH + tid];
        unsigned long long vB = 0;
        if (t > 0 && rem) vB = __hip_atomic_load(slotB, __ATOMIC_RELAXED, __HIP_MEMORY_SCOPE_AGENT);

        {
            float p0 = 0.f, p1 = 0.f, p2 = 0.f, p3 = 0.f;
            const float4* h4 = (const float4*)&hsA[kb];
#pragma unroll
            for (int r4 = 0; r4 < 32; ++r4) {
                float4 hv = h4[r4];
                p0 = fmaf(w[4 * r4 + 0], hv.x, p0);
                p1 = fmaf(w[4 * r4 + 1], hv.y, p1);
                p2 = fmaf(w[4 * r4 + 2], hv.z, p2);
                p3 = fmaf(w[4 * r4 + 3], hv.w, p3);
            }
            float pA = (p0 + p1) + (p2 + p3);
            if (kg) red[kg - 1][jl] = pA;
            __syncthreads();
            if (kg == 0) {
                float v = pA + red[0][jl] + red[1][jl] + red[2][jl] + xwA;
                float hn = 1.f - 2.f / (__expf(2.f * v) + 1.f);
                unsigned long long pv =
                    (((unsigned long long)(unsigned)(t + 1)) << 32) |
                    (unsigned long long)__float_as_uint(hn);
                __hip_atomic_store(&hbuf2[((unsigned)t & 1u) * (NB * HH) + gA * HH + j], pv,
                                   __ATOMIC_RELAXED, __HIP_MEMORY_SCOPE_AGENT);
                hsA[j] = hn;
                out[(gA * TT + t) * HH + j] = hn;
                if (t + 1 < TT) xwA = out[(gA * TT + t + 1) * HH + j];
            }
            if (t > 0 && rem) {
                while ((unsigned)(vB >> 32) != (unsigned)t)
                    vB = __hip_atomic_load(slotB, __ATOMIC_RELAXED, __HIP_MEMORY_SCOPE_AGENT);
                hsB[tid] = __uint_as_float((unsigned)vB);
            }
            __syncthreads();
        }

        // ================= phase B: produce B(t), stage A(t) ===============
        // early-issue poll for A(t): stored with tag t+1 at slot t&1
        const unsigned long long* slotA =
            &hbuf2[(((unsigned)t) & 1u) * (NB * HH) + gA * HH + tid];
        unsigned long long vA = 0;
        if (rem) vA = __hip_atomic_load(slotA, __ATOMIC_RELAXED, __HIP_MEMORY_SCOPE_AGENT);

        {
            float p0 = 0.f, p1 = 0.f, p2 = 0.f, p3 = 0.f;
            const float4* h4 = (const float4*)&hsB[kb];
#pragma unroll
            for (int r4 = 0; r4 < 32; ++r4) {
                float4 hv = h4[r4];
                p0 = fmaf(w[4 * r4 + 0], hv.x, p0);
                p1 = fmaf(w[4 * r4 + 1], hv.y, p1);
                p2 = fmaf(w[4 * r4 + 2], hv.z, p2);
                p3 = fmaf(w[4 * r4 + 3], hv.w, p3);
            }
            float pB = (p0 + p1) + (p2 + p3);
            if (kg) red[kg - 1][jl] = pB;
            __syncthreads();
            if (kg == 0) {
                float v = pB + red[0][jl] + red[1][jl] + red[2][jl] + xwB;
                float hn = 1.f - 2.f / (__expf(2.f * v) + 1.f);
                unsigned long long pv =
                    (((unsigned long long)(unsigned)(t + 1)) << 32) |
                    (unsigned long long)__float_as_uint(hn);
                __hip_atomic_store(&hbuf2[((unsigned)t & 1u) * (NB * HH) + gB * HH + j], pv,
                                   __ATOMIC_RELAXED, __HIP_MEMORY_SCOPE_AGENT);
                hsB[j] = hn;
                out[(gB * TT + t) * HH + j] = hn;
                if (t + 1 < TT) xwB = out[(gB * TT + t + 1) * HH + j];
            }
            if (rem) {
                while ((unsigned)(vA >> 32) != (unsigned)(t + 1))
                    vA = __hip_atomic_load(slotA, __ATOMIC_RELAXED, __HIP_MEMORY_SCOPE_AGENT);
                hsA[tid] = __uint_as_float((unsigned)vA);
            }
            __syncthreads();
        }
    }
}

// ---------------------------------------------------------------------------
extern "C" void kernel_launch(void* const* d_in, const int* in_sizes, int n_in,
                              void* d_out, int out_size, void* d_ws, size_t ws_size,
                              hipStream_t stream) {
    (void)in_sizes; (void)n_in; (void)out_size; (void)ws_size;
    const float* x  = (const float*)d_in[0];
    const float* h0 = (const float*)d_in[1];
    const float* Wx = (const float*)d_in[2];
    const float* Wh = (const float*)d_in[3];
    const float* bv = (const float*)d_in[4];
    float* out = (float*)d_out;

    // workspace layout
    unsigned long long* hbuf2 = (unsigned long long*)d_ws;            // 2*64*512*8 = 512 KiB
    unsigned short* Wt = (unsigned short*)((char*)d_ws + 2 * NB * HH * sizeof(unsigned long long)); // 1 MiB

    // zero the tag words (tag 0 never matches any expected tag >= 1)
    hipMemsetAsync(hbuf2, 0, 2 * NB * HH * sizeof(unsigned long long), stream);

    // 1) split+transpose Wx -> Wt (bf16 hi|lo, B^T layout)
    wt_kernel<<<64, 256, 0, stream>>>(Wx, Wt);

    // 2) projection GEMM: d_out = x @ Wx + b  (split-bf16 MFMA, fp32-accurate)
    proj_kernel<<<(32768 / 64) * (HH / 64), 256, 0, stream>>>(x, Wt, bv, out);

    // 3) sequential recurrence, 2 phase-shifted batches per block
    rec_kernel<<<NB * 2, 512, 0, stream>>>(h0, Wh, out, hbuf2);
}

// Round 3
// 898.848 us; speedup vs baseline: 1.3692x; 1.3692x over previous
//
#include <hip/hip_runtime.h>
#include <hip/hip_bf16.h>

// Problem constants
#define NB 64    // batch
#define TT 512   // timesteps
#define HH 512   // hidden
#define DD 512   // input dim

typedef __attribute__((ext_vector_type(8))) __bf16 bf16x8;
typedef __attribute__((ext_vector_type(4))) float f32x4;

__device__ __forceinline__ unsigned short f2bf_rn(float f) {
    union { float f; unsigned u; } v; v.f = f;
    unsigned r = v.u + 0x7FFFu + ((v.u >> 16) & 1u);
    return (unsigned short)(r >> 16);
}
__device__ __forceinline__ float bf2f(unsigned short s) {
    union { unsigned u; float f; } v; v.u = ((unsigned)s) << 16;
    return v.f;
}

// ---------------------------------------------------------------------------
// Kernel 1: Wt[n][k]   = bf16_hi(Wx[k][n])   (n in [0,512), k in [0,512))
//           Wt[n][512+k] = bf16_lo(Wx[k][n])
// ---------------------------------------------------------------------------
__global__ __launch_bounds__(256) void wt_kernel(const float* __restrict__ Wx,
                                                 unsigned short* __restrict__ Wt) {
    const int bk = blockIdx.x >> 3, bn = blockIdx.x & 7;
    const int k0 = bk * 64, n0 = bn * 64;
    __shared__ float tile[64][65];
    const int t = threadIdx.x;
    const int kr = t >> 2, seg = t & 3;
    const float4* src = (const float4*)&Wx[(k0 + kr) * HH + n0 + seg * 16];
    float4 a = src[0], b = src[1], c = src[2], d = src[3];
    float vv[16];
    *(float4*)&vv[0] = a; *(float4*)&vv[4] = b; *(float4*)&vv[8] = c; *(float4*)&vv[12] = d;
#pragma unroll
    for (int q = 0; q < 16; ++q) tile[kr][seg * 16 + q] = vv[q];
    __syncthreads();
    const int nr = t >> 2;
    unsigned hu[8], lu[8];
#pragma unroll
    for (int i = 0; i < 8; ++i) {
        float f0 = tile[seg * 16 + 2 * i + 0][nr];
        float f1 = tile[seg * 16 + 2 * i + 1][nr];
        unsigned short h0 = f2bf_rn(f0); unsigned short l0 = f2bf_rn(f0 - bf2f(h0));
        unsigned short h1 = f2bf_rn(f1); unsigned short l1 = f2bf_rn(f1 - bf2f(h1));
        hu[i] = (unsigned)h0 | ((unsigned)h1 << 16);
        lu[i] = (unsigned)l0 | ((unsigned)l1 << 16);
    }
    unsigned short* dh = &Wt[(n0 + nr) * 1024 + k0 + seg * 16];
    unsigned short* dl = dh + 512;
    ((uint4*)dh)[0] = make_uint4(hu[0], hu[1], hu[2], hu[3]);
    ((uint4*)dh)[1] = make_uint4(hu[4], hu[5], hu[6], hu[7]);
    ((uint4*)dl)[0] = make_uint4(lu[0], lu[1], lu[2], lu[3]);
    ((uint4*)dl)[1] = make_uint4(lu[4], lu[5], lu[6], lu[7]);
}

// ---------------------------------------------------------------------------
// Kernel 2: projection GEMM  out[i][j] = sum_k x[i][k]*Wx[k][j] + b[j]
// split-bf16 (hi*hi + hi*lo + lo*hi) via MFMA, fp32-accurate.
// ---------------------------------------------------------------------------
#define LDA 72
__global__ __launch_bounds__(256) void proj_kernel(const float* __restrict__ x,
                                                   const unsigned short* __restrict__ Wt,
                                                   const float* __restrict__ bias,
                                                   float* __restrict__ out) {
    __shared__ __align__(16) unsigned short a_hi[64 * LDA];
    __shared__ __align__(16) unsigned short a_lo[64 * LDA];
    __shared__ __align__(16) unsigned short b_hi[64 * LDA];
    __shared__ __align__(16) unsigned short b_lo[64 * LDA];

    const int bx = blockIdx.x;
    const int i0 = (bx >> 3) * 64;
    const int n0 = (bx & 7) * 64;
    const int t = threadIdx.x;
    const int row = t >> 2, seg = t & 3;
    const int lane = t & 63, wid = t >> 6;
    const int wm = (wid >> 1) * 32, wn = (wid & 1) * 32;
    const int fr = lane & 15;

    f32x4 acc00 = {0.f, 0.f, 0.f, 0.f}, acc01 = acc00, acc10 = acc00, acc11 = acc00;

    for (int kc = 0; kc < 8; ++kc) {
        __syncthreads();
        {
            const float4* src = (const float4*)&x[(i0 + row) * DD + kc * 64 + seg * 16];
            float4 a = src[0], b = src[1], c = src[2], d = src[3];
            float vv[16];
            *(float4*)&vv[0] = a; *(float4*)&vv[4] = b; *(float4*)&vv[8] = c; *(float4*)&vv[12] = d;
            unsigned hu[8], lu[8];
#pragma unroll
            for (int i = 0; i < 8; ++i) {
                unsigned short h0 = f2bf_rn(vv[2 * i]); unsigned short l0 = f2bf_rn(vv[2 * i] - bf2f(h0));
                unsigned short h1 = f2bf_rn(vv[2 * i + 1]); unsigned short l1 = f2bf_rn(vv[2 * i + 1] - bf2f(h1));
                hu[i] = (unsigned)h0 | ((unsigned)h1 << 16);
                lu[i] = (unsigned)l0 | ((unsigned)l1 << 16);
            }
            uint4* dh = (uint4*)&a_hi[row * LDA + seg * 16];
            uint4* dl = (uint4*)&a_lo[row * LDA + seg * 16];
            dh[0] = make_uint4(hu[0], hu[1], hu[2], hu[3]);
            dh[1] = make_uint4(hu[4], hu[5], hu[6], hu[7]);
            dl[0] = make_uint4(lu[0], lu[1], lu[2], lu[3]);
            dl[1] = make_uint4(lu[4], lu[5], lu[6], lu[7]);
        }
        {
            const uint4* sh = (const uint4*)&Wt[(n0 + row) * 1024 + kc * 64 + seg * 16];
            const uint4* sl = (const uint4*)&Wt[(n0 + row) * 1024 + 512 + kc * 64 + seg * 16];
            uint4 h0v = sh[0], h1v = sh[1], l0v = sl[0], l1v = sl[1];
            uint4* dh = (uint4*)&b_hi[row * LDA + seg * 16];
            uint4* dl = (uint4*)&b_lo[row * LDA + seg * 16];
            dh[0] = h0v; dh[1] = h1v; dl[0] = l0v; dl[1] = l1v;
        }
        __syncthreads();
#pragma unroll
        for (int s = 0; s < 2; ++s) {
            const int ko = s * 32 + (lane >> 4) * 8;
            bf16x8 ah0 = *(const bf16x8*)&a_hi[(wm + fr) * LDA + ko];
            bf16x8 ah1 = *(const bf16x8*)&a_hi[(wm + 16 + fr) * LDA + ko];
            bf16x8 al0 = *(const bf16x8*)&a_lo[(wm + fr) * LDA + ko];
            bf16x8 al1 = *(const bf16x8*)&a_lo[(wm + 16 + fr) * LDA + ko];
            bf16x8 bh0 = *(const bf16x8*)&b_hi[(wn + fr) * LDA + ko];
            bf16x8 bh1 = *(const bf16x8*)&b_hi[(wn + 16 + fr) * LDA + ko];
            bf16x8 bl0 = *(const bf16x8*)&b_lo[(wn + fr) * LDA + ko];
            bf16x8 bl1 = *(const bf16x8*)&b_lo[(wn + 16 + fr) * LDA + ko];
            acc00 = __builtin_amdgcn_mfma_f32_16x16x32_bf16(ah0, bh0, acc00, 0, 0, 0);
            acc00 = __builtin_amdgcn_mfma_f32_16x16x32_bf16(ah0, bl0, acc00, 0, 0, 0);
            acc00 = __builtin_amdgcn_mfma_f32_16x16x32_bf16(al0, bh0, acc00, 0, 0, 0);
            acc01 = __builtin_amdgcn_mfma_f32_16x16x32_bf16(ah0, bh1, acc01, 0, 0, 0);
            acc01 = __builtin_amdgcn_mfma_f32_16x16x32_bf16(ah0, bl1, acc01, 0, 0, 0);
            acc01 = __builtin_amdgcn_mfma_f32_16x16x32_bf16(al0, bh1, acc01, 0, 0, 0);
            acc10 = __builtin_amdgcn_mfma_f32_16x16x32_bf16(ah1, bh0, acc10, 0, 0, 0);
            acc10 = __builtin_amdgcn_mfma_f32_16x16x32_bf16(ah1, bl0, acc10, 0, 0, 0);
            acc10 = __builtin_amdgcn_mfma_f32_16x16x32_bf16(al1, bh0, acc10, 0, 0, 0);
            acc11 = __builtin_amdgcn_mfma_f32_16x16x32_bf16(ah1, bh1, acc11, 0, 0, 0);
            acc11 = __builtin_amdgcn_mfma_f32_16x16x32_bf16(ah1, bl1, acc11, 0, 0, 0);
            acc11 = __builtin_amdgcn_mfma_f32_16x16x32_bf16(al1, bh1, acc11, 0, 0, 0);
        }
    }
    const float bc0 = bias[n0 + wn + fr];
    const float bc1 = bias[n0 + wn + 16 + fr];
#pragma unroll
    for (int r = 0; r < 4; ++r) {
        int rw0 = i0 + wm + (lane >> 4) * 4 + r;
        int rw1 = rw0 + 16;
        out[rw0 * HH + n0 + wn + fr]      = acc00[r] + bc0;
        out[rw0 * HH + n0 + wn + 16 + fr] = acc01[r] + bc1;
        out[rw1 * HH + n0 + wn + fr]      = acc10[r] + bc0;
        out[rw1 * HH + n0 + wn + 16 + fr] = acc11[r] + bc1;
    }
}

// ---------------------------------------------------------------------------
// Kernel 3: recurrence — PARTIAL-SUM SHIPPING. 256 blocks x 512 threads.
// block b: batch g = b&63, k-slice s = b>>6 (rows k in [128s,128s+128) of Wh
// for ALL 512 columns). Thread tid = output column j. w[128] = Wh[ks][j].
//
// Per step t:
//   FMA over the block's OWN h-slice hsl (local, no wait): part[j].
//   Non-owner cols (j>>7 != s): store tagged {tag=t+1, part} 8B word to the
//     column-owner's mailbox pbuf[t&1][g][idx][j].
//   Owner cols (j>>7 == s): poll their 3 remote partials straight into
//     registers (3 parallel loads/iter), sum + own + xw, tanh -> h[j];
//     write out, write hsl[(t+1)&1][jl]. ONE barrier/step (hsl dbuf).
// The block-wide reduction is 3 register adds at the consumer: no LDS
// staging of 384 h values, no red[] reduce barrier.
// Safety: 8B single-copy-atomic words, exact tag, 2-slot dbuf. Every block
// consumes from every other slice-block of its batch each step -> per-batch
// lockstep within +-1 step -> slot reuse (t+2) cannot race an unconsumed t.
// ---------------------------------------------------------------------------
__global__ __launch_bounds__(512, 2) void rec_kernel(const float* __restrict__ h0,
                                                     const float* __restrict__ Wh,
                                                     float* __restrict__ out,
                                                     unsigned long long* __restrict__ pbuf) {
    const int b = blockIdx.x;
    const int g = b & 63;            // batch
    const int s = b >> 6;            // k-slice
    const int j = threadIdx.x;       // output column 0..511
    const int sj = j >> 7;           // owner slice of column j
    const bool owner = (sj == s);    // wave-uniform (128-aligned)
    const int jl = j & 127;
    const int idx = s - (s > sj ? 1 : 0);   // my position among col-j's 3 remotes

    // w[r] = Wh[128s + r][j] (coalesced: consecutive j)
    float w[128];
#pragma unroll
    for (int r = 0; r < 128; ++r) w[r] = Wh[(s * 128 + r) * HH + j];

    __shared__ float hsl[2][128];
    if (j < 128) hsl[0][j] = h0[g * HH + s * 128 + j];

    float xw = owner ? out[(g * TT + 0) * HH + j] : 0.f;
    __syncthreads();

#pragma unroll 1
    for (int t = 0; t < TT; ++t) {
        const int slot = t & 1;
        const unsigned tg = (unsigned)(t + 1);

        // ---- FMA over local k-slice (LDS broadcast reads, 4 accumulators) ----
        float p0 = 0.f, p1 = 0.f, p2 = 0.f, p3 = 0.f;
        const float4* h4 = (const float4*)&hsl[t & 1][0];
#pragma unroll
        for (int r4 = 0; r4 < 32; ++r4) {
            float4 hv = h4[r4];
            p0 = fmaf(w[4 * r4 + 0], hv.x, p0);
            p1 = fmaf(w[4 * r4 + 1], hv.y, p1);
            p2 = fmaf(w[4 * r4 + 2], hv.z, p2);
            p3 = fmaf(w[4 * r4 + 3], hv.w, p3);
        }
        float part = (p0 + p1) + (p2 + p3);

        if (!owner) {
            // ship tagged partial to column owner's mailbox
            unsigned long long pv = ((unsigned long long)tg << 32) |
                                    (unsigned long long)__float_as_uint(part);
            __hip_atomic_store(&pbuf[(((unsigned)slot * NB + g) * 3 + idx) * HH + j], pv,
                               __ATOMIC_RELAXED, __HIP_MEMORY_SCOPE_AGENT);
        } else {
            // prefetch next step's xw while partials are in flight
            float xwn = (t + 1 < TT) ? out[(g * TT + t + 1) * HH + j] : 0.f;
            const unsigned long long* a0 = &pbuf[(((unsigned)slot * NB + g) * 3 + 0) * HH + j];
            const unsigned long long* a1 = a0 + HH;
            const unsigned long long* a2 = a1 + HH;
            unsigned long long v0, v1, v2;
            do {
                v0 = __hip_atomic_load(a0, __ATOMIC_RELAXED, __HIP_MEMORY_SCOPE_AGENT);
                v1 = __hip_atomic_load(a1, __ATOMIC_RELAXED, __HIP_MEMORY_SCOPE_AGENT);
                v2 = __hip_atomic_load(a2, __ATOMIC_RELAXED, __HIP_MEMORY_SCOPE_AGENT);
            } while ((unsigned)(v0 >> 32) != tg || (unsigned)(v1 >> 32) != tg ||
                     (unsigned)(v2 >> 32) != tg);
            float v = part + __uint_as_float((unsigned)v0) + __uint_as_float((unsigned)v1) +
                      __uint_as_float((unsigned)v2) + xw;
            // tanh via exp: exact at saturation, ~1e-7 rel error
            float hn = 1.f - 2.f / (__expf(2.f * v) + 1.f);
            out[(g * TT + t) * HH + j] = hn;
            hsl[(t + 1) & 1][jl] = hn;
            xw = xwn;
        }
        __syncthreads();   // hsl[(t+1)&1] complete before next FMA; dbuf guards laggards
    }
}

// ---------------------------------------------------------------------------
extern "C" void kernel_launch(void* const* d_in, const int* in_sizes, int n_in,
                              void* d_out, int out_size, void* d_ws, size_t ws_size,
                              hipStream_t stream) {
    (void)in_sizes; (void)n_in; (void)out_size; (void)ws_size;
    const float* x  = (const float*)d_in[0];
    const float* h0 = (const float*)d_in[1];
    const float* Wx = (const float*)d_in[2];
    const float* Wh = (const float*)d_in[3];
    const float* bv = (const float*)d_in[4];
    float* out = (float*)d_out;

    // workspace layout
    const size_t PBUF_BYTES = 2ull * NB * 3 * HH * sizeof(unsigned long long); // 1.5 MiB
    unsigned long long* pbuf = (unsigned long long*)d_ws;
    unsigned short* Wt = (unsigned short*)((char*)d_ws + PBUF_BYTES);          // +1 MiB

    // zero mailbox tags (tag 0 never matches any expected tag >= 1)
    hipMemsetAsync(pbuf, 0, PBUF_BYTES, stream);

    // 1) split+transpose Wx -> Wt (bf16 hi|lo, B^T layout)
    wt_kernel<<<64, 256, 0, stream>>>(Wx, Wt);

    // 2) projection GEMM: d_out = x @ Wx + b  (split-bf16 MFMA, fp32-accurate)
    proj_kernel<<<(32768 / 64) * (HH / 64), 256, 0, stream>>>(x, Wt, bv, out);

    // 3) sequential recurrence, partial-sum shipping
    rec_kernel<<<NB * 4, 512, 0, stream>>>(h0, Wh, out, pbuf);
}